// Round 4
// baseline (43425.250 us; speedup 1.0000x reference)
//
#include <hip/hip_runtime.h>
#include <cstddef>
#include <cstdint>

#define BN_EPS 1e-5f

// ===== weight transpose: w[M][K] -> wT[K][M], 32x32 LDS tiles ===============
__global__ __launch_bounds__(256)
void transpose_w(const float* __restrict__ w, float* __restrict__ wT, int M, int K)
{
    __shared__ float tile[32][33];
    const int k0 = blockIdx.x * 32, m0 = blockIdx.y * 32;
    const int tx = threadIdx.x & 31, ty = threadIdx.x >> 5;   // 32 x 8
#pragma unroll
    for (int r = ty; r < 32; r += 8) {
        int m = m0 + r, k = k0 + tx;
        tile[r][tx] = (m < M && k < K) ? w[(size_t)m * K + k] : 0.0f;
    }
    __syncthreads();
#pragma unroll
    for (int r = ty; r < 32; r += 8) {
        int k = k0 + r, m = m0 + tx;
        if (k < K && m < M) wT[(size_t)k * M + m] = tile[tx][r];
    }
}

// ===== 128x128 tile, 128 threads, 8m x 16n per thread, fp32 implicit GEMM ===
// A (weights, pre-transposed wT[k][co]) and B (im2col) both staged in LDS,
// BK=8 double-buffered, register prefetch, one barrier per chunk.
template<int KW, int STRIDE, int PAD, int CIN, int TIN, int TOUT>
__global__ __launch_bounds__(128, 2)
void conv_bn_relu_t(const float* __restrict__ in, const float* __restrict__ wT,
                    const float* __restrict__ gamma, const float* __restrict__ beta,
                    const float* __restrict__ mean, const float* __restrict__ var,
                    float* __restrict__ out)
{
    constexpr int BK = 8;
    constexpr int Kg = CIN * KW;          // 240 / 2304 / 3072, all % BK == 0
    constexpr int COUT = 768;

    const int bb  = blockIdx.z;
    const int co0 = blockIdx.x * 128;
    const int t0  = blockIdx.y * 128;
    const int tid = threadIdx.x;

    __shared__ float As[2][BK][132];
    __shared__ float Bs[2][BK][132];

    float acc[8][16] = {};

    const int tx = tid & 7;               // n: tx*4 + {0..3} + 32*{0..3}
    const int ty = tid >> 3;              // m: ty*4 + {0..3} + 64*{0..1}

    const float* __restrict__ inb = in + (size_t)bb * CIN * TIN;

    // staging: thread owns 8 consecutive elems of one kk row (for both A and B)
    const int s_kk = tid >> 4;            // 0..7
    const int s_of = (tid & 15) * 8;      // 0..120
    float rA[8], rB[8];

    auto loadA = [&](int kc) {
        const float* p = wT + (size_t)(kc + s_kk) * COUT + co0 + s_of;
        float4 a0 = *reinterpret_cast<const float4*>(p);
        float4 a1 = *reinterpret_cast<const float4*>(p + 4);
        rA[0] = a0.x; rA[1] = a0.y; rA[2] = a0.z; rA[3] = a0.w;
        rA[4] = a1.x; rA[5] = a1.y; rA[6] = a1.z; rA[7] = a1.w;
    };
    auto loadB = [&](int kc) {
        int cik = kc + s_kk;
        int ci  = cik / KW;               // KW compile-time
        int kw  = cik - ci * KW;
        const float* __restrict__ pc = inb + (size_t)ci * TIN;
        int tin0 = (t0 + s_of) * STRIDE + kw - PAD;
#pragma unroll
        for (int j = 0; j < 8; ++j) {
            int tin = tin0 + j * STRIDE;
            rB[j] = (tin >= 0 && tin < TIN) ? pc[tin] : 0.0f;
        }
    };
    auto storeAB = [&](int pp) {
        *reinterpret_cast<float4*>(&As[pp][s_kk][s_of])     = make_float4(rA[0], rA[1], rA[2], rA[3]);
        *reinterpret_cast<float4*>(&As[pp][s_kk][s_of + 4]) = make_float4(rA[4], rA[5], rA[6], rA[7]);
        *reinterpret_cast<float4*>(&Bs[pp][s_kk][s_of])     = make_float4(rB[0], rB[1], rB[2], rB[3]);
        *reinterpret_cast<float4*>(&Bs[pp][s_kk][s_of + 4]) = make_float4(rB[4], rB[5], rB[6], rB[7]);
    };

    loadA(0); loadB(0); storeAB(0);
    loadA(BK); loadB(BK);                 // prefetch chunk 1 into regs
    __syncthreads();

    int p = 0;
    for (int kc = 0; kc < Kg; kc += BK) {
        if (kc + BK < Kg) storeAB(p ^ 1);

#pragma unroll
        for (int kk = 0; kk < BK; ++kk) {
            float4 a0 = *reinterpret_cast<const float4*>(&As[p][kk][ty * 4]);
            float4 a1 = *reinterpret_cast<const float4*>(&As[p][kk][ty * 4 + 64]);
            float4 b0 = *reinterpret_cast<const float4*>(&Bs[p][kk][tx * 4]);
            float4 b1 = *reinterpret_cast<const float4*>(&Bs[p][kk][tx * 4 + 32]);
            float4 b2 = *reinterpret_cast<const float4*>(&Bs[p][kk][tx * 4 + 64]);
            float4 b3 = *reinterpret_cast<const float4*>(&Bs[p][kk][tx * 4 + 96]);
            float a[8]  = {a0.x, a0.y, a0.z, a0.w, a1.x, a1.y, a1.z, a1.w};
            float bv[16] = {b0.x, b0.y, b0.z, b0.w, b1.x, b1.y, b1.z, b1.w,
                            b2.x, b2.y, b2.z, b2.w, b3.x, b3.y, b3.z, b3.w};
#pragma unroll
            for (int mi = 0; mi < 8; ++mi)
#pragma unroll
                for (int nj = 0; nj < 16; ++nj)
                    acc[mi][nj] = fmaf(a[mi], bv[nj], acc[mi][nj]);
        }
        __syncthreads();                  // Bs[p] reads + Bs[p^1] writes drained
        if (kc + 2 * BK < Kg) { loadA(kc + 2 * BK); loadB(kc + 2 * BK); }
        p ^= 1;
    }

#pragma unroll
    for (int mi = 0; mi < 8; ++mi) {
        int co = co0 + ty * 4 + (mi & 3) + 64 * (mi >> 2);
        float g  = gamma[co], be = beta[co], mu = mean[co], va = var[co];
        float inv = g / sqrtf(va + BN_EPS);
        float sh  = be - mu * inv;
        float* op = out + ((size_t)bb * COUT + co) * TOUT;
#pragma unroll
        for (int jb = 0; jb < 4; ++jb) {
            int t = t0 + tx * 4 + 32 * jb;
            float4 v;
            v.x = acc[mi][jb * 4 + 0] * inv + sh;  v.x = v.x > 0.0f ? v.x : 0.0f;
            v.y = acc[mi][jb * 4 + 1] * inv + sh;  v.y = v.y > 0.0f ? v.y : 0.0f;
            v.z = acc[mi][jb * 4 + 2] * inv + sh;  v.z = v.z > 0.0f ? v.z : 0.0f;
            v.w = acc[mi][jb * 4 + 3] * inv + sh;  v.w = v.w > 0.0f ? v.w : 0.0f;
            if (t + 3 < TOUT) {
                *reinterpret_cast<float4*>(&op[t]) = v;
            } else {
                float e[4] = {v.x, v.y, v.z, v.w};
                for (int q = 0; q < 4; ++q) if (t + q < TOUT) op[t + q] = e[q];
            }
        }
    }
}

// ================= 1x1 conv (C=768 -> D=64) + bias, output z[b][t][d] =======
constexpr int TM = 64, TN = 64, TK = 16;

__global__ __launch_bounds__(256)
void conv1x1_bias_T(const float* __restrict__ in, const float* __restrict__ w,
                    const float* __restrict__ bias, float* __restrict__ z,
                    int Cin, int T)
{
    const int b   = blockIdx.z;
    const int t0  = blockIdx.y * TN;
    const int tid = threadIdx.x;

    __shared__ float As[TK][TM + 4];
    __shared__ float Bs[TK][TN + 4];

    float acc[4][4] = {};

    const int m0 = (tid & 15) * 4;
    const int n0 = (tid >> 4) * 4;

    const float* __restrict__ inb = in + (size_t)b * Cin * T;

    const int a_m = tid >> 4;
    const int a_k = tid & 15;
    const int b_k = tid >> 6;
    const int b_n = tid & 63;

    for (int kc = 0; kc < Cin; kc += TK) {
        __syncthreads();
#pragma unroll
        for (int i = 0; i < 4; ++i) {
            int m = a_m + 16 * i;
            As[a_k][m] = w[(size_t)m * Cin + kc + a_k];
        }
#pragma unroll
        for (int i = 0; i < 4; ++i) {
            int kk = b_k + 4 * i;
            int ci = kc + kk;
            int t  = t0 + b_n;
            Bs[kk][b_n] = (t < T) ? inb[(size_t)ci * T + t] : 0.0f;
        }
        __syncthreads();
#pragma unroll
        for (int kk = 0; kk < TK; ++kk) {
            float4 av = *reinterpret_cast<const float4*>(&As[kk][m0]);
            float4 bv = *reinterpret_cast<const float4*>(&Bs[kk][n0]);
            float am[4] = {av.x, av.y, av.z, av.w};
            float bn[4] = {bv.x, bv.y, bv.z, bv.w};
#pragma unroll
            for (int mi = 0; mi < 4; ++mi)
#pragma unroll
                for (int nj = 0; nj < 4; ++nj)
                    acc[mi][nj] = fmaf(am[mi], bn[nj], acc[mi][nj]);
        }
    }

    float4 bb = *reinterpret_cast<const float4*>(&bias[m0]);
    float bs[4] = {bb.x, bb.y, bb.z, bb.w};
#pragma unroll
    for (int nj = 0; nj < 4; ++nj) {
        int t = t0 + n0 + nj;
        if (t < T) {
            float4 v;
            v.x = acc[0][nj] + bs[0];
            v.y = acc[1][nj] + bs[1];
            v.z = acc[2][nj] + bs[2];
            v.w = acc[3][nj] + bs[3];
            *reinterpret_cast<float4*>(&z[((size_t)b * T + t) * 64 + m0]) = v;
        }
    }
}

// ============================== VQ kernels ==================================
__global__ __launch_bounds__(256)
void vq_e2(const float* __restrict__ emb, float* __restrict__ e2)
{
    int m = blockIdx.x * 256 + threadIdx.x;
    if (m < 512) {
        float s = 0.0f;
#pragma unroll
        for (int d = 0; d < 64; ++d) {
            float v = emb[(size_t)m * 64 + d];
            s = fmaf(v, v, s);
        }
        e2[m] = s;
    }
}

__global__ __launch_bounds__(64)
void vq_argmin(const float* __restrict__ z, const float* __restrict__ emb,
               const float* __restrict__ e2, int* __restrict__ idx,
               float* __restrict__ counts, int N)
{
    __shared__ float Es[64 * 64];
    const int tid = threadIdx.x;
    const int n   = blockIdx.x * 64 + tid;
    const bool act = n < N;

    float x[64];
    float x2 = 0.0f;
    if (act) {
        const float4* zp = reinterpret_cast<const float4*>(z + (size_t)n * 64);
#pragma unroll
        for (int i = 0; i < 16; ++i) {
            float4 v = zp[i];
            x[4 * i + 0] = v.x; x[4 * i + 1] = v.y;
            x[4 * i + 2] = v.z; x[4 * i + 3] = v.w;
        }
#pragma unroll
        for (int d = 0; d < 64; ++d) x2 = fmaf(x[d], x[d], x2);
    }

    float best = 3.4e38f;
    int   bi   = 0;
    for (int c = 0; c < 8; ++c) {
        __syncthreads();
        const float4* ep  = reinterpret_cast<const float4*>(emb + (size_t)c * 4096);
        float4*       esp = reinterpret_cast<float4*>(Es);
#pragma unroll
        for (int i = 0; i < 16; ++i) esp[tid + 64 * i] = ep[tid + 64 * i];
        __syncthreads();
        for (int r = 0; r < 64; ++r) {
            const float4* er = reinterpret_cast<const float4*>(&Es[r * 64]);
            float dot = 0.0f;
#pragma unroll
            for (int i = 0; i < 16; ++i) {
                float4 e4 = er[i];
                dot = fmaf(x[4 * i + 0], e4.x, dot);
                dot = fmaf(x[4 * i + 1], e4.y, dot);
                dot = fmaf(x[4 * i + 2], e4.z, dot);
                dot = fmaf(x[4 * i + 3], e4.w, dot);
            }
            float dist = (e2[c * 64 + r] + x2) - 2.0f * dot;  // reference op order
            if (dist < best) { best = dist; bi = c * 64 + r; }
        }
    }
    if (act) {
        idx[n] = bi;
        atomicAdd(&counts[bi], 1.0f);
    }
}

__global__ __launch_bounds__(256)
void vq_quant_loss(const float* __restrict__ z, const float* __restrict__ emb,
                   const int* __restrict__ idx, float* __restrict__ qout,
                   double* __restrict__ loss_sum, int Ntot)
{
    int g = blockIdx.x * 256 + threadIdx.x;
    float d2 = 0.0f;
    if (g < Ntot) {
        int n = g >> 6;
        int d = g & 63;
        float q  = emb[(size_t)idx[n] * 64 + d];
        float zv = z[g];
        qout[g] = zv + (q - zv);
        float diff = zv - q;
        d2 = diff * diff;
    }
#pragma unroll
    for (int o = 32; o > 0; o >>= 1) d2 += __shfl_down(d2, o);
    __shared__ float wsum[4];
    if ((threadIdx.x & 63) == 0) wsum[threadIdx.x >> 6] = d2;
    __syncthreads();
    if (threadIdx.x == 0)
        atomicAdd(loss_sum, (double)(wsum[0] + wsum[1] + wsum[2] + wsum[3]));
}

__global__ __launch_bounds__(512)
void vq_finalize(const float* __restrict__ counts, const double* __restrict__ loss_sum,
                 float* __restrict__ out, int Ntot, int Npts)
{
    int t = threadIdx.x;
    float c   = counts[t];
    float avg = c / (float)Npts;
    float term = avg * logf(avg + 1e-10f);
#pragma unroll
    for (int o = 32; o > 0; o >>= 1) term += __shfl_down(term, o);
    __shared__ float wsum[8];
    if ((t & 63) == 0) wsum[t >> 6] = term;
    __syncthreads();
    if (t == 0) {
        float s = 0.0f;
        for (int i = 0; i < 8; ++i) s += wsum[i];
        out[Ntot]     = 0.25f * (float)(loss_sum[0] / (double)Ntot);
        out[Ntot + 1] = expf(-s);
    }
}

// ================================ launcher ==================================
extern "C" void kernel_launch(void* const* d_in, const int* in_sizes, int n_in,
                              void* d_out, int out_size, void* d_ws, size_t ws_size,
                              hipStream_t stream)
{
    const float* mels     = (const float*)d_in[0];
    const float* w1       = (const float*)d_in[1];
    const float* w2       = (const float*)d_in[2];
    const float* w3       = (const float*)d_in[3];
    const float* w4       = (const float*)d_in[4];
    const float* w5       = (const float*)d_in[5];
    const float* w6       = (const float*)d_in[6];
    const float* b6       = (const float*)d_in[7];
    const float* bn_gamma = (const float*)d_in[8];
    const float* bn_beta  = (const float*)d_in[9];
    const float* bn_mean  = (const float*)d_in[10];
    const float* bn_var   = (const float*)d_in[11];
    const float* emb      = (const float*)d_in[12];

    constexpr int B = 32, C = 768, D = 64;
    constexpr int T1 = 1022, T2 = 511;
    constexpr size_t ACT = (size_t)B * C * T1;

    char* ws = (char*)d_ws;
    float*  bufA   = (float*)ws;
    float*  bufB   = (float*)(ws + ACT * 4);
    size_t  zoff   = 2 * ACT * 4;
    float*  z      = (float*)(ws + zoff);
    size_t  idxoff = zoff + (size_t)B * T2 * D * 4;
    int*    idx    = (int*)(ws + idxoff);
    size_t  e2off  = idxoff + (size_t)B * T2 * 4;
    float*  e2p    = (float*)(ws + e2off);
    size_t  cntoff = e2off + 512 * 4;
    float*  counts = (float*)(ws + cntoff);
    double* lossp  = (double*)(ws + cntoff + 512 * 4);
    size_t  wtoff  = cntoff + 512 * 4 + 64;       // aligned
    float*  wT     = (float*)(ws + wtoff);        // max 3072*768 floats = 9.4 MB

    hipMemsetAsync(ws + cntoff, 0, 512 * 4 + 8, stream);

    vq_e2<<<dim3(2), 256, 0, stream>>>(emb, e2p);

    // conv1: Kg = 240
    transpose_w<<<dim3(8, 24), 256, 0, stream>>>(w1, wT, C, 240);
    conv_bn_relu_t<3, 1, 0, 80, 1024, 1022><<<dim3(6, 8, B), 128, 0, stream>>>(
        mels, wT, bn_gamma + 0 * C, bn_beta + 0 * C, bn_mean + 0 * C, bn_var + 0 * C, bufA);
    // conv2: Kg = 2304
    transpose_w<<<dim3(72, 24), 256, 0, stream>>>(w2, wT, C, 2304);
    conv_bn_relu_t<3, 1, 1, 768, 1022, 1022><<<dim3(6, 8, B), 128, 0, stream>>>(
        bufA, wT, bn_gamma + 1 * C, bn_beta + 1 * C, bn_mean + 1 * C, bn_var + 1 * C, bufB);
    // conv3: Kg = 3072, stride 2
    transpose_w<<<dim3(96, 24), 256, 0, stream>>>(w3, wT, C, 3072);
    conv_bn_relu_t<4, 2, 1, 768, 1022, 511><<<dim3(6, 4, B), 128, 0, stream>>>(
        bufB, wT, bn_gamma + 2 * C, bn_beta + 2 * C, bn_mean + 2 * C, bn_var + 2 * C, bufA);
    // conv4
    transpose_w<<<dim3(72, 24), 256, 0, stream>>>(w4, wT, C, 2304);
    conv_bn_relu_t<3, 1, 1, 768, 511, 511><<<dim3(6, 4, B), 128, 0, stream>>>(
        bufA, wT, bn_gamma + 3 * C, bn_beta + 3 * C, bn_mean + 3 * C, bn_var + 3 * C, bufB);
    // conv5
    transpose_w<<<dim3(72, 24), 256, 0, stream>>>(w5, wT, C, 2304);
    conv_bn_relu_t<3, 1, 1, 768, 511, 511><<<dim3(6, 4, B), 128, 0, stream>>>(
        bufB, wT, bn_gamma + 4 * C, bn_beta + 4 * C, bn_mean + 4 * C, bn_var + 4 * C, bufA);

    conv1x1_bias_T<<<dim3(1, 8, B), 256, 0, stream>>>(bufA, w6, b6, z, C, T2);

    const int Npts = B * T2;
    const int Ntot = Npts * D;
    vq_argmin<<<dim3((Npts + 63) / 64), 64, 0, stream>>>(z, emb, e2p, idx, counts, Npts);
    vq_quant_loss<<<dim3(Ntot / 256), 256, 0, stream>>>(z, emb, idx, (float*)d_out, lossp, Ntot);
    vq_finalize<<<dim3(1), 512, 0, stream>>>(counts, lossp, (float*)d_out, Ntot, Npts);
}

// Round 5
// 8419.051 us; speedup vs baseline: 5.1580x; 5.1580x over previous
//
#include <hip/hip_runtime.h>
#include <cstddef>
#include <cstdint>

#define BN_EPS 1e-5f

// ===== weight transpose: w[M][K] -> wT[K][M], 32x32 LDS tiles ===============
__global__ __launch_bounds__(256)
void transpose_w(const float* __restrict__ w, float* __restrict__ wT, int M, int K)
{
    __shared__ float tile[32][33];
    const int k0 = blockIdx.x * 32, m0 = blockIdx.y * 32;
    const int tx = threadIdx.x & 31, ty = threadIdx.x >> 5;   // 32 x 8
#pragma unroll
    for (int r = ty; r < 32; r += 8) {
        int m = m0 + r, k = k0 + tx;
        tile[r][tx] = (m < M && k < K) ? w[(size_t)m * K + k] : 0.0f;
    }
    __syncthreads();
#pragma unroll
    for (int r = ty; r < 32; r += 8) {
        int k = k0 + r, m = m0 + tx;
        if (k < K && m < M) wT[(size_t)k * M + m] = tile[tx][r];
    }
}

// ===== 128x128 tile, 128 threads, 8m x 16n per thread, fp32 implicit GEMM ===
// A (weights, pre-transposed wT[k][co]) and B (im2col) both staged in LDS,
// BK=8 double-buffered, register prefetch, one barrier per chunk.
// NOTE: plain __launch_bounds__(128). The (128,2) variant capped the
// allocator at 128 VGPRs -> acc[8][16] spilled to scratch (34 GB HBM traffic,
// VALUBusy 5%). ~190 VGPRs needed; 256 cap => no spill, 2 waves/SIMD.
template<int KW, int STRIDE, int PAD, int CIN, int TIN, int TOUT>
__global__ __launch_bounds__(128)
void conv_bn_relu_t(const float* __restrict__ in, const float* __restrict__ wT,
                    const float* __restrict__ gamma, const float* __restrict__ beta,
                    const float* __restrict__ mean, const float* __restrict__ var,
                    float* __restrict__ out)
{
    constexpr int BK = 8;
    constexpr int Kg = CIN * KW;          // 240 / 2304 / 3072, all % BK == 0
    constexpr int COUT = 768;

    const int bb  = blockIdx.z;
    const int co0 = blockIdx.x * 128;
    const int t0  = blockIdx.y * 128;
    const int tid = threadIdx.x;

    __shared__ float As[2][BK][132];
    __shared__ float Bs[2][BK][132];

    float acc[8][16] = {};

    const int tx = tid & 7;               // n: tx*4 + {0..3} + 32*{0..3}
    const int ty = tid >> 3;              // m: ty*4 + {0..3} + 64*{0..1}

    const float* __restrict__ inb = in + (size_t)bb * CIN * TIN;

    // staging: thread owns 8 consecutive elems of one kk row (for both A and B)
    const int s_kk = tid >> 4;            // 0..7
    const int s_of = (tid & 15) * 8;      // 0..120
    float rA[8], rB[8];

    auto loadA = [&](int kc) {
        const float* p = wT + (size_t)(kc + s_kk) * COUT + co0 + s_of;
        float4 a0 = *reinterpret_cast<const float4*>(p);
        float4 a1 = *reinterpret_cast<const float4*>(p + 4);
        rA[0] = a0.x; rA[1] = a0.y; rA[2] = a0.z; rA[3] = a0.w;
        rA[4] = a1.x; rA[5] = a1.y; rA[6] = a1.z; rA[7] = a1.w;
    };
    auto loadB = [&](int kc) {
        int cik = kc + s_kk;
        int ci  = cik / KW;               // KW compile-time
        int kw  = cik - ci * KW;
        const float* __restrict__ pc = inb + (size_t)ci * TIN;
        int tin0 = (t0 + s_of) * STRIDE + kw - PAD;
#pragma unroll
        for (int j = 0; j < 8; ++j) {
            int tin = tin0 + j * STRIDE;
            rB[j] = (tin >= 0 && tin < TIN) ? pc[tin] : 0.0f;
        }
    };
    auto storeAB = [&](int pp) {
        *reinterpret_cast<float4*>(&As[pp][s_kk][s_of])     = make_float4(rA[0], rA[1], rA[2], rA[3]);
        *reinterpret_cast<float4*>(&As[pp][s_kk][s_of + 4]) = make_float4(rA[4], rA[5], rA[6], rA[7]);
        *reinterpret_cast<float4*>(&Bs[pp][s_kk][s_of])     = make_float4(rB[0], rB[1], rB[2], rB[3]);
        *reinterpret_cast<float4*>(&Bs[pp][s_kk][s_of + 4]) = make_float4(rB[4], rB[5], rB[6], rB[7]);
    };

    loadA(0); loadB(0); storeAB(0);
    loadA(BK); loadB(BK);                 // prefetch chunk 1 into regs
    __syncthreads();

    int p = 0;
    for (int kc = 0; kc < Kg; kc += BK) {
        if (kc + BK < Kg) storeAB(p ^ 1);

#pragma unroll
        for (int kk = 0; kk < BK; ++kk) {
            float4 a0 = *reinterpret_cast<const float4*>(&As[p][kk][ty * 4]);
            float4 a1 = *reinterpret_cast<const float4*>(&As[p][kk][ty * 4 + 64]);
            float4 b0 = *reinterpret_cast<const float4*>(&Bs[p][kk][tx * 4]);
            float4 b1 = *reinterpret_cast<const float4*>(&Bs[p][kk][tx * 4 + 32]);
            float4 b2 = *reinterpret_cast<const float4*>(&Bs[p][kk][tx * 4 + 64]);
            float4 b3 = *reinterpret_cast<const float4*>(&Bs[p][kk][tx * 4 + 96]);
            float a[8]  = {a0.x, a0.y, a0.z, a0.w, a1.x, a1.y, a1.z, a1.w};
            float bv[16] = {b0.x, b0.y, b0.z, b0.w, b1.x, b1.y, b1.z, b1.w,
                            b2.x, b2.y, b2.z, b2.w, b3.x, b3.y, b3.z, b3.w};
#pragma unroll
            for (int mi = 0; mi < 8; ++mi)
#pragma unroll
                for (int nj = 0; nj < 16; ++nj)
                    acc[mi][nj] = fmaf(a[mi], bv[nj], acc[mi][nj]);
        }
        __syncthreads();                  // Bs[p] reads + Bs[p^1] writes drained
        if (kc + 2 * BK < Kg) { loadA(kc + 2 * BK); loadB(kc + 2 * BK); }
        p ^= 1;
    }

#pragma unroll
    for (int mi = 0; mi < 8; ++mi) {
        int co = co0 + ty * 4 + (mi & 3) + 64 * (mi >> 2);
        float g  = gamma[co], be = beta[co], mu = mean[co], va = var[co];
        float inv = g / sqrtf(va + BN_EPS);
        float sh  = be - mu * inv;
        float* op = out + ((size_t)bb * COUT + co) * TOUT;
#pragma unroll
        for (int jb = 0; jb < 4; ++jb) {
            int t = t0 + tx * 4 + 32 * jb;
            float4 v;
            v.x = acc[mi][jb * 4 + 0] * inv + sh;  v.x = v.x > 0.0f ? v.x : 0.0f;
            v.y = acc[mi][jb * 4 + 1] * inv + sh;  v.y = v.y > 0.0f ? v.y : 0.0f;
            v.z = acc[mi][jb * 4 + 2] * inv + sh;  v.z = v.z > 0.0f ? v.z : 0.0f;
            v.w = acc[mi][jb * 4 + 3] * inv + sh;  v.w = v.w > 0.0f ? v.w : 0.0f;
            if (t + 3 < TOUT) {
                *reinterpret_cast<float4*>(&op[t]) = v;
            } else {
                float e[4] = {v.x, v.y, v.z, v.w};
                for (int q = 0; q < 4; ++q) if (t + q < TOUT) op[t + q] = e[q];
            }
        }
    }
}

// ================= 1x1 conv (C=768 -> D=64) + bias, output z[b][t][d] =======
constexpr int TM = 64, TN = 64, TK = 16;

__global__ __launch_bounds__(256)
void conv1x1_bias_T(const float* __restrict__ in, const float* __restrict__ w,
                    const float* __restrict__ bias, float* __restrict__ z,
                    int Cin, int T)
{
    const int b   = blockIdx.z;
    const int t0  = blockIdx.y * TN;
    const int tid = threadIdx.x;

    __shared__ float As[TK][TM + 4];
    __shared__ float Bs[TK][TN + 4];

    float acc[4][4] = {};

    const int m0 = (tid & 15) * 4;
    const int n0 = (tid >> 4) * 4;

    const float* __restrict__ inb = in + (size_t)b * Cin * T;

    const int a_m = tid >> 4;
    const int a_k = tid & 15;
    const int b_k = tid >> 6;
    const int b_n = tid & 63;

    for (int kc = 0; kc < Cin; kc += TK) {
        __syncthreads();
#pragma unroll
        for (int i = 0; i < 4; ++i) {
            int m = a_m + 16 * i;
            As[a_k][m] = w[(size_t)m * Cin + kc + a_k];
        }
#pragma unroll
        for (int i = 0; i < 4; ++i) {
            int kk = b_k + 4 * i;
            int ci = kc + kk;
            int t  = t0 + b_n;
            Bs[kk][b_n] = (t < T) ? inb[(size_t)ci * T + t] : 0.0f;
        }
        __syncthreads();
#pragma unroll
        for (int kk = 0; kk < TK; ++kk) {
            float4 av = *reinterpret_cast<const float4*>(&As[kk][m0]);
            float4 bv = *reinterpret_cast<const float4*>(&Bs[kk][n0]);
            float am[4] = {av.x, av.y, av.z, av.w};
            float bn[4] = {bv.x, bv.y, bv.z, bv.w};
#pragma unroll
            for (int mi = 0; mi < 4; ++mi)
#pragma unroll
                for (int nj = 0; nj < 4; ++nj)
                    acc[mi][nj] = fmaf(am[mi], bn[nj], acc[mi][nj]);
        }
    }

    float4 bb = *reinterpret_cast<const float4*>(&bias[m0]);
    float bs[4] = {bb.x, bb.y, bb.z, bb.w};
#pragma unroll
    for (int nj = 0; nj < 4; ++nj) {
        int t = t0 + n0 + nj;
        if (t < T) {
            float4 v;
            v.x = acc[0][nj] + bs[0];
            v.y = acc[1][nj] + bs[1];
            v.z = acc[2][nj] + bs[2];
            v.w = acc[3][nj] + bs[3];
            *reinterpret_cast<float4*>(&z[((size_t)b * T + t) * 64 + m0]) = v;
        }
    }
}

// ============================== VQ kernels ==================================
__global__ __launch_bounds__(256)
void vq_e2(const float* __restrict__ emb, float* __restrict__ e2)
{
    int m = blockIdx.x * 256 + threadIdx.x;
    if (m < 512) {
        float s = 0.0f;
#pragma unroll
        for (int d = 0; d < 64; ++d) {
            float v = emb[(size_t)m * 64 + d];
            s = fmaf(v, v, s);
        }
        e2[m] = s;
    }
}

__global__ __launch_bounds__(64)
void vq_argmin(const float* __restrict__ z, const float* __restrict__ emb,
               const float* __restrict__ e2, int* __restrict__ idx,
               float* __restrict__ counts, int N)
{
    __shared__ float Es[64 * 64];
    const int tid = threadIdx.x;
    const int n   = blockIdx.x * 64 + tid;
    const bool act = n < N;

    float x[64];
    float x2 = 0.0f;
    if (act) {
        const float4* zp = reinterpret_cast<const float4*>(z + (size_t)n * 64);
#pragma unroll
        for (int i = 0; i < 16; ++i) {
            float4 v = zp[i];
            x[4 * i + 0] = v.x; x[4 * i + 1] = v.y;
            x[4 * i + 2] = v.z; x[4 * i + 3] = v.w;
        }
#pragma unroll
        for (int d = 0; d < 64; ++d) x2 = fmaf(x[d], x[d], x2);
    }

    float best = 3.4e38f;
    int   bi   = 0;
    for (int c = 0; c < 8; ++c) {
        __syncthreads();
        const float4* ep  = reinterpret_cast<const float4*>(emb + (size_t)c * 4096);
        float4*       esp = reinterpret_cast<float4*>(Es);
#pragma unroll
        for (int i = 0; i < 16; ++i) esp[tid + 64 * i] = ep[tid + 64 * i];
        __syncthreads();
        for (int r = 0; r < 64; ++r) {
            const float4* er = reinterpret_cast<const float4*>(&Es[r * 64]);
            float dot = 0.0f;
#pragma unroll
            for (int i = 0; i < 16; ++i) {
                float4 e4 = er[i];
                dot = fmaf(x[4 * i + 0], e4.x, dot);
                dot = fmaf(x[4 * i + 1], e4.y, dot);
                dot = fmaf(x[4 * i + 2], e4.z, dot);
                dot = fmaf(x[4 * i + 3], e4.w, dot);
            }
            float dist = (e2[c * 64 + r] + x2) - 2.0f * dot;  // reference op order
            if (dist < best) { best = dist; bi = c * 64 + r; }
        }
    }
    if (act) {
        idx[n] = bi;
        atomicAdd(&counts[bi], 1.0f);
    }
}

__global__ __launch_bounds__(256)
void vq_quant_loss(const float* __restrict__ z, const float* __restrict__ emb,
                   const int* __restrict__ idx, float* __restrict__ qout,
                   double* __restrict__ loss_sum, int Ntot)
{
    int g = blockIdx.x * 256 + threadIdx.x;
    float d2 = 0.0f;
    if (g < Ntot) {
        int n = g >> 6;
        int d = g & 63;
        float q  = emb[(size_t)idx[n] * 64 + d];
        float zv = z[g];
        qout[g] = zv + (q - zv);
        float diff = zv - q;
        d2 = diff * diff;
    }
#pragma unroll
    for (int o = 32; o > 0; o >>= 1) d2 += __shfl_down(d2, o);
    __shared__ float wsum[4];
    if ((threadIdx.x & 63) == 0) wsum[threadIdx.x >> 6] = d2;
    __syncthreads();
    if (threadIdx.x == 0)
        atomicAdd(loss_sum, (double)(wsum[0] + wsum[1] + wsum[2] + wsum[3]));
}

__global__ __launch_bounds__(512)
void vq_finalize(const float* __restrict__ counts, const double* __restrict__ loss_sum,
                 float* __restrict__ out, int Ntot, int Npts)
{
    int t = threadIdx.x;
    float c   = counts[t];
    float avg = c / (float)Npts;
    float term = avg * logf(avg + 1e-10f);
#pragma unroll
    for (int o = 32; o > 0; o >>= 1) term += __shfl_down(term, o);
    __shared__ float wsum[8];
    if ((t & 63) == 0) wsum[t >> 6] = term;
    __syncthreads();
    if (t == 0) {
        float s = 0.0f;
        for (int i = 0; i < 8; ++i) s += wsum[i];
        out[Ntot]     = 0.25f * (float)(loss_sum[0] / (double)Ntot);
        out[Ntot + 1] = expf(-s);
    }
}

// ================================ launcher ==================================
extern "C" void kernel_launch(void* const* d_in, const int* in_sizes, int n_in,
                              void* d_out, int out_size, void* d_ws, size_t ws_size,
                              hipStream_t stream)
{
    const float* mels     = (const float*)d_in[0];
    const float* w1       = (const float*)d_in[1];
    const float* w2       = (const float*)d_in[2];
    const float* w3       = (const float*)d_in[3];
    const float* w4       = (const float*)d_in[4];
    const float* w5       = (const float*)d_in[5];
    const float* w6       = (const float*)d_in[6];
    const float* b6       = (const float*)d_in[7];
    const float* bn_gamma = (const float*)d_in[8];
    const float* bn_beta  = (const float*)d_in[9];
    const float* bn_mean  = (const float*)d_in[10];
    const float* bn_var   = (const float*)d_in[11];
    const float* emb      = (const float*)d_in[12];

    constexpr int B = 32, C = 768, D = 64;
    constexpr int T1 = 1022, T2 = 511;
    constexpr size_t ACT = (size_t)B * C * T1;

    char* ws = (char*)d_ws;
    float*  bufA   = (float*)ws;
    float*  bufB   = (float*)(ws + ACT * 4);
    size_t  zoff   = 2 * ACT * 4;
    float*  z      = (float*)(ws + zoff);
    size_t  idxoff = zoff + (size_t)B * T2 * D * 4;
    int*    idx    = (int*)(ws + idxoff);
    size_t  e2off  = idxoff + (size_t)B * T2 * 4;
    float*  e2p    = (float*)(ws + e2off);
    size_t  cntoff = e2off + 512 * 4;
    float*  counts = (float*)(ws + cntoff);
    double* lossp  = (double*)(ws + cntoff + 512 * 4);
    size_t  wtoff  = cntoff + 512 * 4 + 64;       // aligned
    float*  wT     = (float*)(ws + wtoff);        // max 3072*768 floats = 9.4 MB

    hipMemsetAsync(ws + cntoff, 0, 512 * 4 + 8, stream);

    vq_e2<<<dim3(2), 256, 0, stream>>>(emb, e2p);

    // conv1: Kg = 240
    transpose_w<<<dim3(8, 24), 256, 0, stream>>>(w1, wT, C, 240);
    conv_bn_relu_t<3, 1, 0, 80, 1024, 1022><<<dim3(6, 8, B), 128, 0, stream>>>(
        mels, wT, bn_gamma + 0 * C, bn_beta + 0 * C, bn_mean + 0 * C, bn_var + 0 * C, bufA);
    // conv2: Kg = 2304
    transpose_w<<<dim3(72, 24), 256, 0, stream>>>(w2, wT, C, 2304);
    conv_bn_relu_t<3, 1, 1, 768, 1022, 1022><<<dim3(6, 8, B), 128, 0, stream>>>(
        bufA, wT, bn_gamma + 1 * C, bn_beta + 1 * C, bn_mean + 1 * C, bn_var + 1 * C, bufB);
    // conv3: Kg = 3072, stride 2
    transpose_w<<<dim3(96, 24), 256, 0, stream>>>(w3, wT, C, 3072);
    conv_bn_relu_t<4, 2, 1, 768, 1022, 511><<<dim3(6, 4, B), 128, 0, stream>>>(
        bufB, wT, bn_gamma + 2 * C, bn_beta + 2 * C, bn_mean + 2 * C, bn_var + 2 * C, bufA);
    // conv4
    transpose_w<<<dim3(72, 24), 256, 0, stream>>>(w4, wT, C, 2304);
    conv_bn_relu_t<3, 1, 1, 768, 511, 511><<<dim3(6, 4, B), 128, 0, stream>>>(
        bufA, wT, bn_gamma + 3 * C, bn_beta + 3 * C, bn_mean + 3 * C, bn_var + 3 * C, bufB);
    // conv5
    transpose_w<<<dim3(72, 24), 256, 0, stream>>>(w5, wT, C, 2304);
    conv_bn_relu_t<3, 1, 1, 768, 511, 511><<<dim3(6, 4, B), 128, 0, stream>>>(
        bufB, wT, bn_gamma + 4 * C, bn_beta + 4 * C, bn_mean + 4 * C, bn_var + 4 * C, bufA);

    conv1x1_bias_T<<<dim3(1, 8, B), 256, 0, stream>>>(bufA, w6, b6, z, C, T2);

    const int Npts = B * T2;
    const int Ntot = Npts * D;
    vq_argmin<<<dim3((Npts + 63) / 64), 64, 0, stream>>>(z, emb, e2p, idx, counts, Npts);
    vq_quant_loss<<<dim3(Ntot / 256), 256, 0, stream>>>(z, emb, idx, (float*)d_out, lossp, Ntot);
    vq_finalize<<<dim3(1), 512, 0, stream>>>(counts, lossp, (float*)d_out, Ntot, Npts);
}

// Round 7
// 3197.350 us; speedup vs baseline: 13.5816x; 2.6331x over previous
//
#include <hip/hip_runtime.h>
#include <cstddef>
#include <cstdint>

#define BN_EPS 1e-5f

typedef _Float16 half8 __attribute__((ext_vector_type(8)));
typedef float f32x4v __attribute__((ext_vector_type(4)));

// pack fp32 (pre-scaled) into fp16 high/low split: v = h + l/2048
__device__ __forceinline__ unsigned split_pack(float v) {
    _Float16 h = (_Float16)v;
    float r = (v - (float)h) * 2048.0f;
    _Float16 l = (_Float16)r;
    unsigned short hu = __builtin_bit_cast(unsigned short, h);
    unsigned short lu = __builtin_bit_cast(unsigned short, l);
    return (unsigned)hu | ((unsigned)lu << 16);
}

// ===== prep: w[co][ci][kw] fp32 -> Wp[kw][co][CIPAD] packed u32, scaled x256
__global__ __launch_bounds__(256)
void prep_w(const float* __restrict__ w, unsigned* __restrict__ wp,
            int Cin, int KW, int CIPAD)
{
    int id = blockIdx.x * 256 + threadIdx.x;
    int total = KW * 768 * CIPAD;
    if (id >= total) return;
    int cip = id % CIPAD;
    int co  = (id / CIPAD) % 768;
    int kw  = id / (CIPAD * 768);
    float v = 0.0f;
    if (cip < Cin) v = w[((size_t)co * Cin + cip) * KW + kw];
    wp[id] = split_pack(v * 256.0f);
}

// ===== prep: mels[b][80][1024] fp32 -> melsT[b][1032][96] packed, scaled x16
__global__ __launch_bounds__(256)
void prep_mels(const float* __restrict__ mels, unsigned* __restrict__ mt)
{
    int id = blockIdx.x * 256 + threadIdx.x;
    if (id >= 32 * 1032 * 96) return;
    int c = id % 96;
    int t = (id / 96) % 1032;
    int b = id / (96 * 1032);
    float v = 0.0f;
    if (c < 80 && t < 1024) v = mels[((size_t)b * 80 + c) * 1024 + t];
    mt[id] = split_pack(v * 16.0f);
}

// ===== fp16x3-split MFMA conv + BN + ReLU =====================================
// Block 256 thr (4 waves), tile 128co x 128t, wave tile 64x64 (4x4 of 16x16x32).
// A = weights (scale 256), B = activations (scale 16), both packed h|l u32.
// result = (accHH + accCROSS/2048)/4096.
// C/D layout (m89-verified): col(n)=lane&15, row(m)=quad*4+reg.
// EPI=0: write packed [t][768] u32; EPI=1 (conv5): write fp32 [co][TOUT].
template<int KW, int S, int P, int CIPAD, int TIN, int TSIN, int TOUT, int TSOUT, int EPI>
__global__ __launch_bounds__(256)
void conv_mfma(const unsigned* __restrict__ Xin, const unsigned* __restrict__ Wp,
               const float* __restrict__ gamma, const float* __restrict__ beta,
               const float* __restrict__ mean, const float* __restrict__ var,
               unsigned* __restrict__ Uout, float* __restrict__ Fout)
{
    constexpr int NCI = CIPAD / 32;
    constexpr int NC  = KW * NCI;
    __shared__ unsigned smem[16896];           // 67584 B (frag planes 40KB / bounce 66KB)
    _Float16* sm = (_Float16*)smem;
    constexpr int AH = 0, AL = 5120, BH = 10240, BL = 15360;  // f16 units, rows of 40

    const int b   = blockIdx.z;
    const int co0 = blockIdx.x * 128;
    const int t0  = blockIdx.y * 128;
    const int tid = threadIdx.x;
    const int lane = tid & 63, wv = tid >> 6;
    const int quad = lane >> 4, l16 = lane & 15;
    const int wm = (wv & 1) * 64, wn = (wv >> 1) * 64;

    f32x4v accH[4][4] = {};
    f32x4v accX[4][4] = {};

    const int srow = tid & 127, shalf = tid >> 7;
    const unsigned* __restrict__ xb = Xin + (size_t)b * TSIN * CIPAD;

    auto store_planes = [&](const uint4 v[4], int offH, int offL) {
        const int sw = srow & 3;
        unsigned q[16] = {v[0].x, v[0].y, v[0].z, v[0].w, v[1].x, v[1].y, v[1].z, v[1].w,
                          v[2].x, v[2].y, v[2].z, v[2].w, v[3].x, v[3].y, v[3].z, v[3].w};
#pragma unroll
        for (int g = 0; g < 2; ++g) {
            const unsigned* p = q + g * 8;
            uint4 hw, lw;
            hw.x = (p[0] & 0xffffu) | (p[1] << 16);
            hw.y = (p[2] & 0xffffu) | (p[3] << 16);
            hw.z = (p[4] & 0xffffu) | (p[5] << 16);
            hw.w = (p[6] & 0xffffu) | (p[7] << 16);
            lw.x = (p[0] >> 16) | (p[1] & 0xffff0000u);
            lw.y = (p[2] >> 16) | (p[3] & 0xffff0000u);
            lw.z = (p[4] >> 16) | (p[5] & 0xffff0000u);
            lw.w = (p[6] >> 16) | (p[7] & 0xffff0000u);
            int gl  = shalf * 2 + g;
            int col = ((gl ^ sw) * 8);              // swizzled 16B chunk
            *(uint4*)(sm + offH + srow * 40 + col) = hw;
            *(uint4*)(sm + offL + srow * 40 + col) = lw;
        }
    };

    for (int c = 0; c < NC; ++c) {
        const int kw  = c / NCI;
        const int ci0 = (c % NCI) * 32;

        // global -> reg (A: weights; B: activations, zero-filled out of range)
        const uint4* pa = (const uint4*)(Wp + (size_t)(kw * 768 + co0 + srow) * CIPAD + ci0 + shalf * 16);
        uint4 av[4] = {pa[0], pa[1], pa[2], pa[3]};
        const int tp = (t0 + srow) * S + kw - P;
        uint4 bv[4] = {};
        if ((unsigned)tp < (unsigned)TIN) {
            const uint4* pb = (const uint4*)(xb + (size_t)tp * CIPAD + ci0 + shalf * 16);
            bv[0] = pb[0]; bv[1] = pb[1]; bv[2] = pb[2]; bv[3] = pb[3];
        }

        __syncthreads();                           // prior chunk's frag reads done
        store_planes(av, AH, AL);
        store_planes(bv, BH, BL);
        __syncthreads();

        half8 bh[4], bl[4];
#pragma unroll
        for (int nt = 0; nt < 4; ++nt) {
            int n = wn + nt * 16 + l16;
            int col = ((quad ^ (n & 3)) * 8);
            bh[nt] = *(const half8*)(sm + BH + n * 40 + col);
            bl[nt] = *(const half8*)(sm + BL + n * 40 + col);
        }
#pragma unroll
        for (int mt = 0; mt < 4; ++mt) {
            int m = wm + mt * 16 + l16;
            int col = ((quad ^ (m & 3)) * 8);
            half8 ah = *(const half8*)(sm + AH + m * 40 + col);
            half8 al = *(const half8*)(sm + AL + m * 40 + col);
#pragma unroll
            for (int nt = 0; nt < 4; ++nt) {
                accH[mt][nt] = __builtin_amdgcn_mfma_f32_16x16x32_f16(ah, bh[nt], accH[mt][nt], 0, 0, 0);
                accX[mt][nt] = __builtin_amdgcn_mfma_f32_16x16x32_f16(ah, bl[nt], accX[mt][nt], 0, 0, 0);
                accX[mt][nt] = __builtin_amdgcn_mfma_f32_16x16x32_f16(al, bh[nt], accX[mt][nt], 0, 0, 0);
            }
        }
    }

    __syncthreads();                               // all frag reads done; reuse smem
    if constexpr (EPI == 0) {
        unsigned* bb = smem;                       // bounce: [t_local][co_local], stride 132
#pragma unroll
        for (int mt = 0; mt < 4; ++mt) {
#pragma unroll
            for (int r = 0; r < 4; ++r) {
                int mloc = wm + mt * 16 + quad * 4 + r;   // C/D row = co_local
                int co = co0 + mloc;
                float iv = gamma[co] / sqrtf(var[co] + BN_EPS);
                float sh = beta[co] - mean[co] * iv;
#pragma unroll
                for (int nt = 0; nt < 4; ++nt) {
                    float vf = (accH[mt][nt][r] + accX[mt][nt][r] * (1.0f / 2048.0f)) * (1.0f / 4096.0f);
                    float y = fmaf(vf, iv, sh);
                    y = y > 0.0f ? y : 0.0f;
                    // C/D col = t_local.  BUGFIX (R6): bounce must be [t][co],
                    // previous round wrote [co][t] -> per-tile transposed z.
                    bb[(wn + nt * 16 + l16) * 132 + mloc] = split_pack(y * 16.0f);
                }
            }
        }
        __syncthreads();
        int tl = tid >> 1, seg = tid & 1;
        int t = t0 + tl;
        if (t < TOUT) {
            uint4* dst = (uint4*)(Uout + ((size_t)b * TSOUT + t) * 768 + co0 + seg * 64);
            const uint4* src = (const uint4*)(bb + tl * 132 + seg * 64);
#pragma unroll
            for (int i = 0; i < 16; ++i) dst[i] = src[i];
        }
    } else {
#pragma unroll
        for (int mt = 0; mt < 4; ++mt) {
#pragma unroll
            for (int r = 0; r < 4; ++r) {
                int co = co0 + wm + mt * 16 + quad * 4 + r;
                float iv = gamma[co] / sqrtf(var[co] + BN_EPS);
                float sh = beta[co] - mean[co] * iv;
                float* op = Fout + ((size_t)b * 768 + co) * TOUT;
#pragma unroll
                for (int nt = 0; nt < 4; ++nt) {
                    int t = t0 + wn + nt * 16 + l16;
                    if (t < TOUT) {
                        float vf = (accH[mt][nt][r] + accX[mt][nt][r] * (1.0f / 2048.0f)) * (1.0f / 4096.0f);
                        float y = fmaf(vf, iv, sh);
                        op[t] = y > 0.0f ? y : 0.0f;
                    }
                }
            }
        }
    }
}

// ================= 1x1 conv (C=768 -> D=64) + bias, output z[b][t][d] =======
constexpr int TM = 64, TN = 64, TK = 16;

__global__ __launch_bounds__(256)
void conv1x1_bias_T(const float* __restrict__ in, const float* __restrict__ w,
                    const float* __restrict__ bias, float* __restrict__ z,
                    int Cin, int T)
{
    const int b   = blockIdx.z;
    const int t0  = blockIdx.y * TN;
    const int tid = threadIdx.x;

    __shared__ float As[TK][TM + 4];
    __shared__ float Bs[TK][TN + 4];

    float acc[4][4] = {};

    const int m0 = (tid & 15) * 4;
    const int n0 = (tid >> 4) * 4;

    const float* __restrict__ inb = in + (size_t)b * Cin * T;

    const int a_m = tid >> 4;
    const int a_k = tid & 15;
    const int b_k = tid >> 6;
    const int b_n = tid & 63;

    for (int kc = 0; kc < Cin; kc += TK) {
        __syncthreads();
#pragma unroll
        for (int i = 0; i < 4; ++i) {
            int m = a_m + 16 * i;
            As[a_k][m] = w[(size_t)m * Cin + kc + a_k];
        }
#pragma unroll
        for (int i = 0; i < 4; ++i) {
            int kk = b_k + 4 * i;
            int ci = kc + kk;
            int t  = t0 + b_n;
            Bs[kk][b_n] = (t < T) ? inb[(size_t)ci * T + t] : 0.0f;
        }
        __syncthreads();
#pragma unroll
        for (int kk = 0; kk < TK; ++kk) {
            float4 av = *reinterpret_cast<const float4*>(&As[kk][m0]);
            float4 bv = *reinterpret_cast<const float4*>(&Bs[kk][n0]);
            float am[4] = {av.x, av.y, av.z, av.w};
            float bn[4] = {bv.x, bv.y, bv.z, bv.w};
#pragma unroll
            for (int mi = 0; mi < 4; ++mi)
#pragma unroll
                for (int nj = 0; nj < 4; ++nj)
                    acc[mi][nj] = fmaf(am[mi], bn[nj], acc[mi][nj]);
        }
    }

    float4 bb = *reinterpret_cast<const float4*>(&bias[m0]);
    float bs[4] = {bb.x, bb.y, bb.z, bb.w};
#pragma unroll
    for (int nj = 0; nj < 4; ++nj) {
        int t = t0 + n0 + nj;
        if (t < T) {
            float4 v;
            v.x = acc[0][nj] + bs[0];
            v.y = acc[1][nj] + bs[1];
            v.z = acc[2][nj] + bs[2];
            v.w = acc[3][nj] + bs[3];
            *reinterpret_cast<float4*>(&z[((size_t)b * T + t) * 64 + m0]) = v;
        }
    }
}

// ============================== VQ kernels ==================================
__global__ __launch_bounds__(256)
void vq_e2(const float* __restrict__ emb, float* __restrict__ e2)
{
    int m = blockIdx.x * 256 + threadIdx.x;
    if (m < 512) {
        float s = 0.0f;
#pragma unroll
        for (int d = 0; d < 64; ++d) {
            float v = emb[(size_t)m * 64 + d];
            s = fmaf(v, v, s);
        }
        e2[m] = s;
    }
}

__global__ __launch_bounds__(64)
void vq_argmin(const float* __restrict__ z, const float* __restrict__ emb,
               const float* __restrict__ e2, int* __restrict__ idx,
               float* __restrict__ counts, int N)
{
    __shared__ float Es[64 * 64];
    const int tid = threadIdx.x;
    const int n   = blockIdx.x * 64 + tid;
    const bool act = n < N;

    float x[64];
    float x2 = 0.0f;
    if (act) {
        const float4* zp = reinterpret_cast<const float4*>(z + (size_t)n * 64);
#pragma unroll
        for (int i = 0; i < 16; ++i) {
            float4 v = zp[i];
            x[4 * i + 0] = v.x; x[4 * i + 1] = v.y;
            x[4 * i + 2] = v.z; x[4 * i + 3] = v.w;
        }
#pragma unroll
        for (int d = 0; d < 64; ++d) x2 = fmaf(x[d], x[d], x2);
    }

    float best = 3.4e38f;
    int   bi   = 0;
    for (int c = 0; c < 8; ++c) {
        __syncthreads();
        const float4* ep  = reinterpret_cast<const float4*>(emb + (size_t)c * 4096);
        float4*       esp = reinterpret_cast<float4*>(Es);
#pragma unroll
        for (int i = 0; i < 16; ++i) esp[tid + 64 * i] = ep[tid + 64 * i];
        __syncthreads();
        for (int r = 0; r < 64; ++r) {
            const float4* er = reinterpret_cast<const float4*>(&Es[r * 64]);
            float dot = 0.0f;
#pragma unroll
            for (int i = 0; i < 16; ++i) {
                float4 e4 = er[i];
                dot = fmaf(x[4 * i + 0], e4.x, dot);
                dot = fmaf(x[4 * i + 1], e4.y, dot);
                dot = fmaf(x[4 * i + 2], e4.z, dot);
                dot = fmaf(x[4 * i + 3], e4.w, dot);
            }
            float dist = (e2[c * 64 + r] + x2) - 2.0f * dot;  // reference op order
            if (dist < best) { best = dist; bi = c * 64 + r; }
        }
    }
    if (act) {
        idx[n] = bi;
        atomicAdd(&counts[bi], 1.0f);
    }
}

__global__ __launch_bounds__(256)
void vq_quant_loss(const float* __restrict__ z, const float* __restrict__ emb,
                   const int* __restrict__ idx, float* __restrict__ qout,
                   double* __restrict__ loss_sum, int Ntot)
{
    int g = blockIdx.x * 256 + threadIdx.x;
    float d2 = 0.0f;
    if (g < Ntot) {
        int n = g >> 6;
        int d = g & 63;
        float q  = emb[(size_t)idx[n] * 64 + d];
        float zv = z[g];
        qout[g] = zv + (q - zv);
        float diff = zv - q;
        d2 = diff * diff;
    }
#pragma unroll
    for (int o = 32; o > 0; o >>= 1) d2 += __shfl_down(d2, o);
    __shared__ float wsum[4];
    if ((threadIdx.x & 63) == 0) wsum[threadIdx.x >> 6] = d2;
    __syncthreads();
    if (threadIdx.x == 0)
        atomicAdd(loss_sum, (double)(wsum[0] + wsum[1] + wsum[2] + wsum[3]));
}

__global__ __launch_bounds__(512)
void vq_finalize(const float* __restrict__ counts, const double* __restrict__ loss_sum,
                 float* __restrict__ out, int Ntot, int Npts)
{
    int t = threadIdx.x;
    float c   = counts[t];
    float avg = c / (float)Npts;
    float term = avg * logf(avg + 1e-10f);
#pragma unroll
    for (int o = 32; o > 0; o >>= 1) term += __shfl_down(term, o);
    __shared__ float wsum[8];
    if ((t & 63) == 0) wsum[t >> 6] = term;
    __syncthreads();
    if (t == 0) {
        float s = 0.0f;
        for (int i = 0; i < 8; ++i) s += wsum[i];
        out[Ntot]     = 0.25f * (float)(loss_sum[0] / (double)Ntot);
        out[Ntot + 1] = expf(-s);
    }
}

// ================================ launcher ==================================
extern "C" void kernel_launch(void* const* d_in, const int* in_sizes, int n_in,
                              void* d_out, int out_size, void* d_ws, size_t ws_size,
                              hipStream_t stream)
{
    const float* mels     = (const float*)d_in[0];
    const float* w1       = (const float*)d_in[1];
    const float* w2       = (const float*)d_in[2];
    const float* w3       = (const float*)d_in[3];
    const float* w4       = (const float*)d_in[4];
    const float* w5       = (const float*)d_in[5];
    const float* w6       = (const float*)d_in[6];
    const float* b6       = (const float*)d_in[7];
    const float* bn_gamma = (const float*)d_in[8];
    const float* bn_beta  = (const float*)d_in[9];
    const float* bn_mean  = (const float*)d_in[10];
    const float* bn_var   = (const float*)d_in[11];
    const float* emb      = (const float*)d_in[12];

    constexpr int B = 32, C = 768, D = 64, T2 = 511;

    char* ws = (char*)d_ws;
    unsigned* P1 = (unsigned*)ws;                      // 100,663,296 B
    unsigned* P2 = (unsigned*)(ws + 100663296);        // 100,663,296 B
    unsigned* Wp = (unsigned*)(ws + 201326592);        // 9,437,184 B (max: conv3)
    size_t misc  = 201326592 + 9437184;
    float*  counts = (float*)(ws + misc);              // 2048 B
    double* lossp  = (double*)(ws + misc + 2048);      // 8 B (+pad)
    float*  e2p    = (float*)(ws + misc + 2048 + 64);  // 2048 B
    int*    idx    = (int*)(ws + misc + 2048 + 64 + 2048);  // 65,408 B

    unsigned* melsT = P2;                              // alias (dead before conv2 out)
    float*    bufA  = (float*)P1;                      // conv5 fp32 out (x3 dead)
    float*    z     = (float*)P2;                      // conv6 out (x4 dead)

    hipMemsetAsync(ws + misc, 0, 2048 + 64, stream);   // counts + loss

    vq_e2<<<dim3(2), 256, 0, stream>>>(emb, e2p);
    prep_mels<<<dim3((32 * 1032 * 96 + 255) / 256), 256, 0, stream>>>(mels, melsT);

    // conv1: Cin 80 (pad 96), KW 3, S1 P0, in melsT[1032][96] -> x1 = P1 [1024][768]
    prep_w<<<dim3((3 * 768 * 96 + 255) / 256), 256, 0, stream>>>(w1, Wp, 80, 3, 96);
    conv_mfma<3, 1, 0, 96, 1032, 1032, 1022, 1024, 0><<<dim3(6, 8, B), 256, 0, stream>>>(
        melsT, Wp, bn_gamma + 0 * C, bn_beta + 0 * C, bn_mean + 0 * C, bn_var + 0 * C, P1, nullptr);
    // conv2: x1(P1) -> x2(P2)
    prep_w<<<dim3((3 * 768 * 768 + 255) / 256), 256, 0, stream>>>(w2, Wp, 768, 3, 768);
    conv_mfma<3, 1, 1, 768, 1022, 1024, 1022, 1024, 0><<<dim3(6, 8, B), 256, 0, stream>>>(
        P1, Wp, bn_gamma + 1 * C, bn_beta + 1 * C, bn_mean + 1 * C, bn_var + 1 * C, P2, nullptr);
    // conv3: stride 2, KW 4: x2(P2) -> x3(P1, stride 512)
    prep_w<<<dim3((4 * 768 * 768 + 255) / 256), 256, 0, stream>>>(w3, Wp, 768, 4, 768);
    conv_mfma<4, 2, 1, 768, 1022, 1024, 511, 512, 0><<<dim3(6, 4, B), 256, 0, stream>>>(
        P2, Wp, bn_gamma + 2 * C, bn_beta + 2 * C, bn_mean + 2 * C, bn_var + 2 * C, P1, nullptr);
    // conv4: x3(P1) -> x4(P2)
    prep_w<<<dim3((3 * 768 * 768 + 255) / 256), 256, 0, stream>>>(w4, Wp, 768, 3, 768);
    conv_mfma<3, 1, 1, 768, 511, 512, 511, 512, 0><<<dim3(6, 4, B), 256, 0, stream>>>(
        P1, Wp, bn_gamma + 3 * C, bn_beta + 3 * C, bn_mean + 3 * C, bn_var + 3 * C, P2, nullptr);
    // conv5: x4(P2) -> bufA fp32 [768][511] (EPI=1)
    prep_w<<<dim3((3 * 768 * 768 + 255) / 256), 256, 0, stream>>>(w5, Wp, 768, 3, 768);
    conv_mfma<3, 1, 1, 768, 511, 512, 511, 511, 1><<<dim3(6, 4, B), 256, 0, stream>>>(
        P2, Wp, bn_gamma + 4 * C, bn_beta + 4 * C, bn_mean + 4 * C, bn_var + 4 * C, nullptr, bufA);

    conv1x1_bias_T<<<dim3(1, 8, B), 256, 0, stream>>>(bufA, w6, b6, z, C, T2);

    const int Npts = B * T2;
    const int Ntot = Npts * D;
    vq_argmin<<<dim3((Npts + 63) / 64), 64, 0, stream>>>(z, emb, e2p, idx, counts, Npts);
    vq_quant_loss<<<dim3(Ntot / 256), 256, 0, stream>>>(z, emb, idx, (float*)d_out, lossp, Ntot);
    vq_finalize<<<dim3(1), 512, 0, stream>>>(counts, lossp, (float*)d_out, Ntot, Npts);
}